// Round 1
// baseline (611.333 us; speedup 1.0000x reference)
//
#include <hip/hip_runtime.h>

#define LOG2E 1.44269504088896340736f
#define LN2   0.69314718055994530942f

// B=256, T=1024, K=64 (fixed by the problem)
__global__ __launch_bounds__(64) void crf_fwd(
    const int*   __restrict__ y,    // (B,T) int32
    const float* __restrict__ em,   // (B,T,K) fp32
    const float* __restrict__ tr,   // (K,K) fp32
    float*       __restrict__ out)  // scalar
{
    constexpr int T = 1024, K = 64;
    const int b = blockIdx.x;
    const int j = threadIdx.x;

    __shared__ float tr_lds[K * K];          // raw transition for t_score lookup
    __shared__ int   y_lds[T];               // this batch's label row
    __shared__ __align__(16) float a_lds[K]; // alpha-exp redistribution buffer

    // ---- one-time staging (single wave per block; syncthreads is cheap) ----
    for (int k = j; k < K * K; k += K) tr_lds[k] = tr[k];
    const int ybase = b * T;
    for (int k = j; k < T; k += K) y_lds[k] = y[ybase + k];
    __syncthreads();

    // lane j holds column j of exp(trans): Texp[i][j], i = 0..63
    float texp[K];
#pragma unroll
    for (int i = 0; i < K; ++i) texp[i] = exp2f(tr_lds[i * K + j] * LOG2E);

    const float* emb = em + (size_t)b * T * K;

    // ---- t = 0 init: alpha0 = emissions[:,0,:] (unmasked) ----
    const float e0 = emb[j];
    float M0 = e0;
#pragma unroll
    for (int o = 32; o > 0; o >>= 1) M0 = fmaxf(M0, __shfl_xor(M0, o, 64));
    float a = exp2f((e0 - M0) * LOG2E - 16.0f);  // exp(e0 - M0) * 2^-16
    float L = M0 + 16.0f * LN2;                  // alpha_j = L + log(a_j)

    const int y0 = y_lds[0];
    float e_part = (y0 != 0 && j == y0) ? e0 : 0.0f;
    float t_part = 0.0f;   // wave-uniform
    int   yprev  = y0;

    a_lds[j] = a;
    __syncthreads();

    // ---- emission prefetch pipeline (depth 4) ----
    float epf[4];
#pragma unroll
    for (int p = 0; p < 4; ++p) epf[p] = emb[(1 + p) * K + j];

    for (int t = 1; t < T; ++t) {
        const int   slot = (t - 1) & 3;
        const float emv  = epf[slot];
        int tn = t + 4; tn = (tn > T - 1) ? (T - 1) : tn;
        epf[slot] = emb[tn * K + j];

        const int yt = y_lds[t];

        // s_j = sum_i a[i] * Texp[i][j]  — 64 fp32 FMAs, 4 accumulators
        float ax = 0.f, ay = 0.f, az = 0.f, aw = 0.f;
#pragma unroll
        for (int i = 0; i < K; i += 4) {
            const float4 av = *(const float4*)(a_lds + i);  // broadcast b128
            ax = fmaf(av.x, texp[i + 0], ax);
            ay = fmaf(av.y, texp[i + 1], ay);
            az = fmaf(av.z, texp[i + 2], az);
            aw = fmaf(av.w, texp[i + 3], aw);
        }
        const float s = (ax + ay) + (az + aw);

        if (yt != 0) {                       // wave-uniform branch
            a = s * exp2f(emv * LOG2E);      // * exp(emit[t,j])
            e_part += (j == yt) ? emv : 0.0f;
            t_part += tr_lds[yprev * K + yt];
        }
        yprev = yt;

        // rescale every 8 steps: max -> 2^-16, fold into L
        if ((t & 7) == 7) {
            float mx = a;
#pragma unroll
            for (int o = 32; o > 0; o >>= 1) mx = fmaxf(mx, __shfl_xor(mx, o, 64));
            const float sc = __builtin_amdgcn_rcpf(mx) * 1.52587890625e-5f; // 2^-16/mx
            a *= sc;
            L += (__log2f(mx) + 16.0f) * LN2;
        }

        __syncthreads();          // all reads of a_lds done (single wave: cheap)
        a_lds[j] = a;
        __syncthreads();          // write visible for next iteration's reads
    }

    // ---- finalize: log_z = L + log(sum_j a_j) ----
    float asum = a, esum = e_part;
#pragma unroll
    for (int o = 32; o > 0; o >>= 1) {
        asum += __shfl_xor(asum, o, 64);
        esum += __shfl_xor(esum, o, 64);
    }
    const float logz = L + __log2f(asum) * LN2;

    if (j == 0) {
        const float ll = esum + t_part - logz;
        atomicAdd(out, ll * (-1.0f / 256.0f));  // -mean over B
    }
}

extern "C" void kernel_launch(void* const* d_in, const int* in_sizes, int n_in,
                              void* d_out, int out_size, void* d_ws, size_t ws_size,
                              hipStream_t stream) {
    const int*   y  = (const int*)d_in[0];
    const float* em = (const float*)d_in[1];
    const float* tr = (const float*)d_in[2];
    float* out = (float*)d_out;

    hipMemsetAsync(out, 0, sizeof(float), stream);
    crf_fwd<<<dim3(256), dim3(64), 0, stream>>>(y, em, tr, out);
}

// Round 2
// 565.723 us; speedup vs baseline: 1.0806x; 1.0806x over previous
//
#include <hip/hip_runtime.h>

typedef float v2f __attribute__((ext_vector_type(2)));

#define LOG2E 1.44269504088896340736f
#define LN2   0.69314718055994530942f

// B=256, T=1024, K=64 (fixed by the problem)
// One wave (64 lanes) per batch; lane j owns output state j.
// NO barriers in the main loop: single wave => LDS pipe is in-order,
// ds_write -> ds_read ordering is guaranteed without s_barrier (and avoids
// the s_waitcnt vmcnt(0) drain that killed the emission prefetch).
__global__ __launch_bounds__(64) void crf_fwd(
    const int*   __restrict__ y,    // (B,T) int32
    const float* __restrict__ em,   // (B,T,K) fp32
    const float* __restrict__ tr,   // (K,K) fp32
    float*       __restrict__ out)  // scalar
{
    constexpr int T = 1024, K = 64;
    const int b = blockIdx.x;
    const int j = threadIdx.x;

    __shared__ float tr_lds[K * K];          // raw transition (t_score lookup)
    __shared__ int   y_lds[T];               // this batch's label row
    __shared__ __align__(16) float a_lds[K]; // alpha-exp redistribution buffer

    // ---- one-time staging ----
    for (int k = j; k < K * K; k += K) tr_lds[k] = tr[k];
    const int ybase = b * T;
    for (int k = j; k < T; k += K) y_lds[k] = y[ybase + k];
    __syncthreads();   // only barrier in the kernel (pre-loop)

    // lane j holds column j of exp(trans) as 32 packed float2
    v2f texp[K / 2];
#pragma unroll
    for (int i = 0; i < K / 2; ++i) {
        texp[i].x = exp2f(tr_lds[(2 * i) * K + j] * LOG2E);
        texp[i].y = exp2f(tr_lds[(2 * i + 1) * K + j] * LOG2E);
    }

    const float* emb = em + (size_t)b * T * K;

    // ---- t = 0 init: alpha0 = emissions[:,0,:] ----
    const float e0 = emb[j];
    float M0 = e0;
#pragma unroll
    for (int o = 32; o > 0; o >>= 1) M0 = fmaxf(M0, __shfl_xor(M0, o, 64));
    float a = exp2f((e0 - M0) * LOG2E - 16.0f);  // exp(e0 - M0) * 2^-16
    float L = M0 + 16.0f * LN2;                  // alpha_j = L + log(a_j)

    const int y0 = y_lds[0];
    float e_part = (y0 != 0 && j == y0) ? e0 : 0.0f;
    float t_part = 0.0f;   // wave-uniform
    int   yprev  = y0;

    a_lds[j] = a;

    // ---- two-stage emission pipeline: raw load 8 ahead, exp 4 ahead ----
    float epf[8];                 // raw em[t,j], slot t&7
#pragma unroll
    for (int s = 1; s <= 8; ++s) {
        int ts = (s > T - 1) ? (T - 1) : s;
        epf[s & 7] = emb[ts * K + j];
    }
    float epx[4], eraw[4];        // exp(em) and raw for step t, slot t&3
#pragma unroll
    for (int s = 1; s <= 4; ++s) {
        float f = epf[s & 7];
        epx[s & 3] = exp2f(f * LOG2E);
        eraw[s & 3] = f;
    }

    for (int t = 1; t < T; ++t) {
        const float ex = epx[t & 3];    // exp(em[t,j])
        const float er = eraw[t & 3];   // em[t,j]

        // refill exp stage for step t+4 (load issued 8 iters ago -> no stall)
        {
            float f = epf[(t + 4) & 7];
            epx[t & 3]  = exp2f(f * LOG2E);
            eraw[t & 3] = f;
        }
        // refill load stage for step t+8
        {
            int tn = t + 8; tn = (tn > T - 1) ? (T - 1) : tn;
            epf[t & 7] = emb[tn * K + j];
        }

        const int yt = y_lds[t];

        // s_j = sum_i a[i] * Texp[i][j] — packed fp32 FMA (v_pk_fma_f32)
        v2f acc0 = {0.f, 0.f}, acc1 = {0.f, 0.f};
#pragma unroll
        for (int i = 0; i < K; i += 4) {
            const float4 av = *(const float4*)(a_lds + i);  // broadcast b128
            v2f lo = {av.x, av.y};
            v2f hi = {av.z, av.w};
            acc0 += lo * texp[i / 2];
            acc1 += hi * texp[i / 2 + 1];
        }
        const float s = (acc0.x + acc0.y) + (acc1.x + acc1.y);

        if (yt != 0) {                       // wave-uniform branch
            a = s * ex;
            e_part += (j == yt) ? er : 0.0f;
            t_part += tr_lds[yprev * K + yt];
        }
        yprev = yt;

        // rescale every 8 steps: max -> 2^-16, fold into L
        if ((t & 7) == 7) {
            float mx = a;
#pragma unroll
            for (int o = 32; o > 0; o >>= 1) mx = fmaxf(mx, __shfl_xor(mx, o, 64));
            const float sc = __builtin_amdgcn_rcpf(mx) * 1.52587890625e-5f; // 2^-16/mx
            a *= sc;
            L += (__log2f(mx) + 16.0f) * LN2;
        }

        a_lds[j] = a;   // in-order LDS pipe orders this vs next iter's reads
    }

    // ---- finalize: log_z = L + log(sum_j a_j) ----
    float asum = a, esum = e_part;
#pragma unroll
    for (int o = 32; o > 0; o >>= 1) {
        asum += __shfl_xor(asum, o, 64);
        esum += __shfl_xor(esum, o, 64);
    }
    const float logz = L + __log2f(asum) * LN2;

    if (j == 0) {
        const float ll = esum + t_part - logz;
        atomicAdd(out, ll * (-1.0f / 256.0f));  // -mean over B
    }
}

extern "C" void kernel_launch(void* const* d_in, const int* in_sizes, int n_in,
                              void* d_out, int out_size, void* d_ws, size_t ws_size,
                              hipStream_t stream) {
    const int*   y  = (const int*)d_in[0];
    const float* em = (const float*)d_in[1];
    const float* tr = (const float*)d_in[2];
    float* out = (float*)d_out;

    hipMemsetAsync(out, 0, sizeof(float), stream);
    crf_fwd<<<dim3(256), dim3(64), 0, stream>>>(y, em, tr, out);
}

// Round 3
// 358.937 us; speedup vs baseline: 1.7032x; 1.5761x over previous
//
#include <hip/hip_runtime.h>

typedef _Float16 half2v __attribute__((ext_vector_type(2)));

#define LOG2E 1.44269504088896340736f
#define LN2   0.69314718055994530942f

static __device__ __forceinline__ float fdot2(half2v a, half2v b, float c) {
#if __has_builtin(__builtin_amdgcn_fdot2)
    return __builtin_amdgcn_fdot2(a, b, c, false);
#else
    return fmaf((float)a.y, (float)b.y, fmaf((float)a.x, (float)b.x, c));
#endif
}

// s_j = sum_i a[i] * Texp[i][j] ; alpha lives in LDS as f16[64] (8 b128 reads)
static __device__ __forceinline__ float dot64(const _Float16* a_sh,
                                              const half2v (&th)[32]) {
    const uint4* pa = (const uint4*)a_sh;
    float ac0 = 0.f, ac1 = 0.f, ac2 = 0.f, ac3 = 0.f;
#pragma unroll
    for (int r = 0; r < 8; ++r) {
        uint4 q = pa[r];                      // broadcast ds_read_b128: 8 halves
        ac0 = fdot2(__builtin_bit_cast(half2v, q.x), th[4 * r + 0], ac0);
        ac1 = fdot2(__builtin_bit_cast(half2v, q.y), th[4 * r + 1], ac1);
        ac2 = fdot2(__builtin_bit_cast(half2v, q.z), th[4 * r + 2], ac2);
        ac3 = fdot2(__builtin_bit_cast(half2v, q.w), th[4 * r + 3], ac3);
    }
    return (ac0 + ac1) + (ac2 + ac3);
}

// B=256, T=1024, K=64. One wave per batch; lane j owns state j.
// Exp-domain forward recursion: A_t = (Texp^T A_{t-1}) .* exp(em_t) * 2^-7,
// L accumulates the log of all folded scale factors. No barriers in loop
// (single wave => DS pipe is in-order). All rotating buffers use constant
// indices (chunk-of-8 full unroll) so they stay in VGPRs — no scratch.
__global__ __launch_bounds__(64) void crf_fwd(
    const int*   __restrict__ yg,   // (B,T) int32
    const float* __restrict__ em,   // (B,T,K) fp32
    const float* __restrict__ tr,   // (K,K) fp32
    float*       __restrict__ out)  // scalar
{
    constexpr int T = 1024, K = 64;
    const int b = blockIdx.x;
    const int j = threadIdx.x;

    __shared__ _Float16 a_sh[K] __attribute__((aligned(16)));

    // lane j holds column j of exp(trans) packed as 32 half2
    half2v th[32];
#pragma unroll
    for (int i = 0; i < 32; ++i) {
        half2v h;
        h.x = (_Float16)exp2f(tr[(2 * i) * K + j] * LOG2E);
        h.y = (_Float16)exp2f(tr[(2 * i + 1) * K + j] * LOG2E);
        th[i] = h;
    }

    const float* emb = em + (size_t)b * T * K;
    const int*   yb  = yg + b * T;

    // ---- t = 0: alpha0 = emissions[:,0,:], centered on its max ----
    const float e0 = emb[j];
    float M0 = e0;
#pragma unroll
    for (int o = 32; o > 0; o >>= 1) M0 = fmaxf(M0, __shfl_xor(M0, o, 64));
    float a = exp2f((e0 - M0) * LOG2E);   // max = 1
    float L = M0;                         // alpha_j = L + log(a_j)

    const int y0 = yb[0];
    float e_part = (y0 != 0 && j == y0) ? e0 : 0.0f;
    float t_part = 0.0f;
    int   nupd   = 0;
    int   yprev  = y0;

    a_sh[j] = (_Float16)a;

    // ---- prefetch t = 1..8 ----
    float ld[8]; int yv[8];
#pragma unroll
    for (int u = 0; u < 8; ++u) { ld[u] = emb[(1 + u) * K + j]; yv[u] = yb[1 + u]; }

    // ---- main loop: 127 chunks of 8 steps (t = 1..1016) ----
    for (int tb = 1; tb <= T - 15; tb += 8) {
        // stage current chunk into fixed registers
        float raw[8], exc[8]; int yc[8];
#pragma unroll
        for (int u = 0; u < 8; ++u) {
            raw[u] = ld[u];
            yc[u]  = yv[u];
            exc[u] = exp2f(ld[u] * LOG2E - 7.0f);   // exp(em) * 2^-7 folded
        }
        // issue next-chunk global prefetch (hidden behind this chunk)
#pragma unroll
        for (int u = 0; u < 8; ++u) {
            int tn = tb + 8 + u; tn = (tn > T - 1) ? (T - 1) : tn;
            ld[u] = emb[tn * K + j];
            yv[u] = yb[tn];
        }
        // masks + transition gathers (loads issued here, consumed after steps)
        bool up[8]; float tvv[8];
        {
            int yp = yprev;
#pragma unroll
            for (int u = 0; u < 8; ++u) {
                const int yt = yc[u];
                up[u]  = (yt != 0);
                tvv[u] = tr[yp * K + yt];   // L1-resident 16 KB table
                yp = yt;
            }
            yprev = yp;
        }

        // ---- 8 serial recursion steps (the critical path) ----
#pragma unroll
        for (int u = 0; u < 8; ++u) {
            const float s  = dot64(a_sh, th);
            const float an = s * exc[u];
            a = up[u] ? an : a;
            a_sh[j] = (_Float16)fminf(a, 60000.0f);  // clamp: no f16 inf
        }

        // ---- off-path bookkeeping ----
#pragma unroll
        for (int u = 0; u < 8; ++u) {
            if (up[u]) {
                t_part += tvv[u];
                nupd   += 1;
                if (j == yc[u]) e_part += raw[u];
            }
        }

        // ---- chunk-end re-centering by exact power of two (wave-uniform) ----
        unsigned ab = (unsigned)__builtin_amdgcn_readlane((int)__float_as_uint(a), 0);
        int ef = (int)((ab >> 23) & 0xFF);
        if (ef > 0 && ef < 255 && ef != 127) {
            const int E = ef - 127;
            const float sc = __uint_as_float((unsigned)(127 - E) << 23); // 2^-E
            a *= sc;
            L += (float)E * LN2;
            a_sh[j] = (_Float16)fminf(a, 60000.0f);
        }
    }

    // ---- tail: t = 1017..1023 (held in ld[0..6]/yv[0..6]) ----
#pragma unroll
    for (int u = 0; u < 7; ++u) {
        const int yt   = yv[u];
        const bool upd = (yt != 0);
        const float tv = tr[yprev * K + yt];
        const float ex = exp2f(ld[u] * LOG2E - 7.0f);
        const float s  = dot64(a_sh, th);
        const float an = s * ex;
        if (upd) {
            t_part += tv;
            nupd   += 1;
            if (j == yt) e_part += ld[u];
        }
        a = upd ? an : a;
        a_sh[j] = (_Float16)fminf(a, 60000.0f);
        yprev = yt;
    }

    L += 7.0f * LN2 * (float)nupd;   // fold the per-update 2^-7 scales

    // ---- finalize: log_z = L + log(sum_j a_j) ----
    float asum = a, esum = e_part;
#pragma unroll
    for (int o = 32; o > 0; o >>= 1) {
        asum += __shfl_xor(asum, o, 64);
        esum += __shfl_xor(esum, o, 64);
    }
    const float logz = L + __log2f(asum) * LN2;

    if (j == 0) {
        const float ll = esum + t_part - logz;
        atomicAdd(out, ll * (-1.0f / 256.0f));  // -mean over B
    }
}

extern "C" void kernel_launch(void* const* d_in, const int* in_sizes, int n_in,
                              void* d_out, int out_size, void* d_ws, size_t ws_size,
                              hipStream_t stream) {
    const int*   y  = (const int*)d_in[0];
    const float* em = (const float*)d_in[1];
    const float* tr = (const float*)d_in[2];
    float* out = (float*)d_out;

    hipMemsetAsync(out, 0, sizeof(float), stream);
    crf_fwd<<<dim3(256), dim3(64), 0, stream>>>(y, em, tr, out);
}